// Round 1
// baseline (955.754 us; speedup 1.0000x reference)
//
#include <hip/hip_runtime.h>
#include <hip/hip_bf16.h>
#include <stdint.h>

#define HID 256
#define GOD 200
#define LN_EPS 1e-5f

__device__ __forceinline__ float bf2f(unsigned short u) {
    union { unsigned int i; float f; } c; c.i = ((unsigned int)u) << 16; return c.f;
}
__device__ __forceinline__ unsigned short f2bf(float f) {
    union { float f; unsigned int i; } c; c.f = f;
    unsigned int x = c.i;
    return (unsigned short)((x + 0x7fffu + ((x >> 16) & 1u)) >> 16);
}
__device__ __forceinline__ unsigned int pack2(float a, float b) {
    return (unsigned int)f2bf(a) | ((unsigned int)f2bf(b) << 16);
}

// ---------------- GEMM 1: go_h = relu(go_x @ Wg + bg), store bf16 ----------------
// block: 256 threads = 128 col-pairs x 2 row-groups(8 rows). tile: 16 rows x 256 cols.
__global__ __launch_bounds__(256) void go_proj_kernel(
        const float* __restrict__ go_x, const float* __restrict__ Wg,
        const float* __restrict__ bg, unsigned short* __restrict__ go_h, int G) {
    __shared__ float xs[16 * GOD];
    int row0 = blockIdx.x * 16;
    int tid = threadIdx.x;
    int nrow = min(16, G - row0);
    const float* src = go_x + (size_t)row0 * GOD;
    for (int i = tid; i < nrow * GOD; i += 256) xs[i] = src[i];
    for (int i = nrow * GOD + tid; i < 16 * GOD; i += 256) xs[i] = 0.f;
    __syncthreads();

    int c  = (tid & 127) * 2;
    int rg = (tid >> 7) * 8;
    float acc[8][2];
#pragma unroll
    for (int r = 0; r < 8; ++r) { acc[r][0] = 0.f; acc[r][1] = 0.f; }

    for (int k = 0; k < GOD; k += 4) {
        float2 w0 = *(const float2*)&Wg[(size_t)(k + 0) * HID + c];
        float2 w1 = *(const float2*)&Wg[(size_t)(k + 1) * HID + c];
        float2 w2 = *(const float2*)&Wg[(size_t)(k + 2) * HID + c];
        float2 w3 = *(const float2*)&Wg[(size_t)(k + 3) * HID + c];
#pragma unroll
        for (int r = 0; r < 8; ++r) {
            float4 x4 = *(const float4*)&xs[(rg + r) * GOD + k];
            acc[r][0] = fmaf(x4.x, w0.x, fmaf(x4.y, w1.x, fmaf(x4.z, w2.x, fmaf(x4.w, w3.x, acc[r][0]))));
            acc[r][1] = fmaf(x4.x, w0.y, fmaf(x4.y, w1.y, fmaf(x4.z, w2.y, fmaf(x4.w, w3.y, acc[r][1]))));
        }
    }
    float bb0 = bg[c], bb1 = bg[c + 1];
#pragma unroll
    for (int r = 0; r < 8; ++r) {
        int row = row0 + rg + r;
        if (row < G) {
            float v0 = fmaxf(acc[r][0] + bb0, 0.f);
            float v1 = fmaxf(acc[r][1] + bb1, 0.f);
            *(unsigned int*)&go_h[(size_t)row * HID + c] = pack2(v0, v1);
        }
    }
}

// ---------------- CSR build ----------------
__global__ void hist_kernel(const int* __restrict__ dst, int* __restrict__ counts, int E) {
    for (int e = blockIdx.x * blockDim.x + threadIdx.x; e < E; e += gridDim.x * blockDim.x)
        atomicAdd(&counts[dst[e]], 1);
}

__global__ __launch_bounds__(1024) void scan_kernel(
        const int* __restrict__ counts, int* __restrict__ offsets,
        int* __restrict__ cursor, int N) {
    __shared__ int wsum[16];
    __shared__ int carry_s;
    int tid = threadIdx.x, lane = tid & 63, wid = tid >> 6;
    if (tid == 0) carry_s = 0;
    __syncthreads();
    for (int base = 0; base < N; base += 1024) {
        int i = base + tid;
        int v = (i < N) ? counts[i] : 0;
        int s = v;
#pragma unroll
        for (int o = 1; o < 64; o <<= 1) { int y = __shfl_up(s, o); if (lane >= o) s += y; }
        if (lane == 63) wsum[wid] = s;
        __syncthreads();
        if (wid == 0) {
            int wv = (lane < 16) ? wsum[lane] : 0;
            int t2 = wv;
#pragma unroll
            for (int o = 1; o < 16; o <<= 1) { int y = __shfl_up(t2, o); if (lane >= o) t2 += y; }
            if (lane < 16) wsum[lane] = t2 - wv;  // exclusive wave prefix
        }
        __syncthreads();
        int excl = carry_s + wsum[wid] + (s - v);
        if (i < N) { offsets[i] = excl; cursor[i] = excl; }
        __syncthreads();
        if (tid == 1023) carry_s += wsum[15] + s;
        __syncthreads();
    }
}

__global__ void scatter_kernel(const int* __restrict__ dst, const int* __restrict__ src,
                               int* __restrict__ cursor, int* __restrict__ nbr, int E) {
    for (int e = blockIdx.x * blockDim.x + threadIdx.x; e < E; e += gridDim.x * blockDim.x) {
        int d = dst[e];
        int slot = atomicAdd(&cursor[d], 1);
        nbr[slot] = src[e];
    }
}

// ---------------- prot_emb -> bf16 into hcat[:, :256] ----------------
__global__ void cast_prot_kernel(const float* __restrict__ prot,
                                 unsigned short* __restrict__ hcat, int N) {
    int total = N * 128;  // uint pairs in first half of each row
    for (int i = blockIdx.x * blockDim.x + threadIdx.x; i < total; i += gridDim.x * blockDim.x) {
        int row = i >> 7, cp = i & 127;
        float2 f = ((const float2*)prot)[(size_t)row * 128 + cp];
        ((unsigned int*)hcat)[(size_t)row * 256 + cp] = pack2(f.x, f.y);
    }
}

// ---------------- scatter-mean: one wave per protein ----------------
__global__ void agg_kernel(const unsigned short* __restrict__ go_h,
                           const int* __restrict__ counts, const int* __restrict__ offsets,
                           const int* __restrict__ nbr, unsigned short* __restrict__ hcat, int N) {
    int p = blockIdx.x;
    if (p >= N) return;
    int lane = threadIdx.x;  // 64
    int deg = counts[p], off = offsets[p];
    float a0 = 0.f, a1 = 0.f, a2 = 0.f, a3 = 0.f;
    for (int i = 0; i < deg; ++i) {
        int g = nbr[off + i];
        ushort4 u = *(const ushort4*)(go_h + (size_t)g * HID + lane * 4);
        a0 += bf2f(u.x); a1 += bf2f(u.y); a2 += bf2f(u.z); a3 += bf2f(u.w);
    }
    float inv = 1.f / (float)max(deg, 1);
    unsigned short* d = hcat + (size_t)p * 512 + HID + lane * 4;
    *(unsigned int*)(d)     = pack2(a0 * inv, a1 * inv);
    *(unsigned int*)(d + 2) = pack2(a2 * inv, a3 * inv);
}

// ---------------- GEMM 2: tmp = relu(hcat @ W1 + b1), bf16 ----------------
__global__ __launch_bounds__(256) void mlp1_kernel(
        const unsigned short* __restrict__ hcat, const float* __restrict__ W1,
        const float* __restrict__ b1, unsigned short* __restrict__ tmp, int N) {
    __shared__ float xs[16 * 512];  // 32 KB
    int row0 = blockIdx.x * 16;
    int tid = threadIdx.x;
    int nrow = min(16, N - row0);
    const unsigned int* srcu = (const unsigned int*)(hcat + (size_t)row0 * 512);
    for (int i = tid; i < nrow * 256; i += 256) {
        unsigned int u = srcu[i];
        float2 f; f.x = bf2f((unsigned short)(u & 0xffffu)); f.y = bf2f((unsigned short)(u >> 16));
        ((float2*)xs)[i] = f;
    }
    for (int i = nrow * 256 + tid; i < 16 * 256; i += 256) {
        float2 z; z.x = 0.f; z.y = 0.f; ((float2*)xs)[i] = z;
    }
    __syncthreads();

    int c  = (tid & 127) * 2;
    int rg = (tid >> 7) * 8;
    float acc[8][2];
#pragma unroll
    for (int r = 0; r < 8; ++r) { acc[r][0] = 0.f; acc[r][1] = 0.f; }

    for (int k = 0; k < 512; k += 4) {
        float2 w0 = *(const float2*)&W1[(size_t)(k + 0) * HID + c];
        float2 w1 = *(const float2*)&W1[(size_t)(k + 1) * HID + c];
        float2 w2 = *(const float2*)&W1[(size_t)(k + 2) * HID + c];
        float2 w3 = *(const float2*)&W1[(size_t)(k + 3) * HID + c];
#pragma unroll
        for (int r = 0; r < 8; ++r) {
            float4 x4 = *(const float4*)&xs[(rg + r) * 512 + k];
            acc[r][0] = fmaf(x4.x, w0.x, fmaf(x4.y, w1.x, fmaf(x4.z, w2.x, fmaf(x4.w, w3.x, acc[r][0]))));
            acc[r][1] = fmaf(x4.x, w0.y, fmaf(x4.y, w1.y, fmaf(x4.z, w2.y, fmaf(x4.w, w3.y, acc[r][1]))));
        }
    }
    float bb0 = b1[c], bb1 = b1[c + 1];
#pragma unroll
    for (int r = 0; r < 8; ++r) {
        int row = row0 + rg + r;
        if (row < N) {
            float v0 = fmaxf(acc[r][0] + bb0, 0.f);
            float v1 = fmaxf(acc[r][1] + bb1, 0.f);
            ((unsigned int*)tmp)[(size_t)row * 128 + (c >> 1)] = pack2(v0, v1);
        }
    }
}

// ---------------- GEMM 3 + residual + LayerNorm ----------------
__global__ __launch_bounds__(256) void mlp2_ln_kernel(
        const unsigned short* __restrict__ tmp, const float* __restrict__ W2,
        const float* __restrict__ b2, const float* __restrict__ prot,
        const int* __restrict__ counts, const float* __restrict__ gamma,
        const float* __restrict__ beta, float* __restrict__ out, int N) {
    __shared__ float xs[16 * 256];  // 16 KB
    __shared__ float ys[16 * 256];  // 16 KB
    int row0 = blockIdx.x * 16;
    int tid = threadIdx.x;
    int nrow = min(16, N - row0);
    const unsigned int* srcu = (const unsigned int*)(tmp + (size_t)row0 * 256);
    for (int i = tid; i < nrow * 128; i += 256) {
        unsigned int u = srcu[i];
        float2 f; f.x = bf2f((unsigned short)(u & 0xffffu)); f.y = bf2f((unsigned short)(u >> 16));
        ((float2*)xs)[i] = f;
    }
    for (int i = nrow * 128 + tid; i < 16 * 128; i += 256) {
        float2 z; z.x = 0.f; z.y = 0.f; ((float2*)xs)[i] = z;
    }
    __syncthreads();

    int c  = (tid & 127) * 2;
    int rg = (tid >> 7) * 8;
    float acc[8][2];
#pragma unroll
    for (int r = 0; r < 8; ++r) { acc[r][0] = 0.f; acc[r][1] = 0.f; }

    for (int k = 0; k < 256; k += 4) {
        float2 w0 = *(const float2*)&W2[(size_t)(k + 0) * HID + c];
        float2 w1 = *(const float2*)&W2[(size_t)(k + 1) * HID + c];
        float2 w2 = *(const float2*)&W2[(size_t)(k + 2) * HID + c];
        float2 w3 = *(const float2*)&W2[(size_t)(k + 3) * HID + c];
#pragma unroll
        for (int r = 0; r < 8; ++r) {
            float4 x4 = *(const float4*)&xs[(rg + r) * 256 + k];
            acc[r][0] = fmaf(x4.x, w0.x, fmaf(x4.y, w1.x, fmaf(x4.z, w2.x, fmaf(x4.w, w3.x, acc[r][0]))));
            acc[r][1] = fmaf(x4.x, w0.y, fmaf(x4.y, w1.y, fmaf(x4.z, w2.y, fmaf(x4.w, w3.y, acc[r][1]))));
        }
    }
    float bb0 = b2[c], bb1 = b2[c + 1];
#pragma unroll
    for (int r = 0; r < 8; ++r) {
        int row = row0 + rg + r;
        if (row < N) {
            float pres = (counts[row] > 0) ? 1.f : 0.f;
            float2 p2 = *(const float2*)&prot[(size_t)row * HID + c];
            ys[(rg + r) * HID + c]     = p2.x + pres * (acc[r][0] + bb0);
            ys[(rg + r) * HID + c + 1] = p2.y + pres * (acc[r][1] + bb1);
        }
    }
    __syncthreads();

    int lane = tid & 63, wid = tid >> 6;
    for (int rr = wid; rr < 16; rr += 4) {
        int row = row0 + rr;
        if (row >= N) continue;
        float v0 = ys[rr * HID + lane];
        float v1 = ys[rr * HID + lane + 64];
        float v2 = ys[rr * HID + lane + 128];
        float v3 = ys[rr * HID + lane + 192];
        float s = v0 + v1 + v2 + v3;
#pragma unroll
        for (int o = 32; o >= 1; o >>= 1) s += __shfl_xor(s, o);
        float mu = s * (1.f / 256.f);
        float d0 = v0 - mu, d1 = v1 - mu, d2 = v2 - mu, d3 = v3 - mu;
        float q = d0 * d0 + d1 * d1 + d2 * d2 + d3 * d3;
#pragma unroll
        for (int o = 32; o >= 1; o >>= 1) q += __shfl_xor(q, o);
        float rstd = rsqrtf(q * (1.f / 256.f) + LN_EPS);
        size_t base = (size_t)row * HID;
        out[base + lane]       = d0 * rstd * gamma[lane]       + beta[lane];
        out[base + lane + 64]  = d1 * rstd * gamma[lane + 64]  + beta[lane + 64];
        out[base + lane + 128] = d2 * rstd * gamma[lane + 128] + beta[lane + 128];
        out[base + lane + 192] = d3 * rstd * gamma[lane + 192] + beta[lane + 192];
    }
}

extern "C" void kernel_launch(void* const* d_in, const int* in_sizes, int n_in,
                              void* d_out, int out_size, void* d_ws, size_t ws_size,
                              hipStream_t stream) {
    const float* prot  = (const float*)d_in[0];
    const float* go_x  = (const float*)d_in[1];
    const int*   edges = (const int*)d_in[2];
    const float* Wg    = (const float*)d_in[4];
    const float* bg    = (const float*)d_in[5];
    const float* W1    = (const float*)d_in[6];
    const float* b1    = (const float*)d_in[7];
    const float* W2    = (const float*)d_in[8];
    const float* b2    = (const float*)d_in[9];
    const float* gamma = (const float*)d_in[10];
    const float* beta  = (const float*)d_in[11];

    int N = in_sizes[0] / HID;
    int G = in_sizes[1] / GOD;
    int E = in_sizes[2] / 2;
    const int* dst = edges;
    const int* src = edges + E;

    uint8_t* w = (uint8_t*)d_ws;
    size_t off = 0;
    auto alloc = [&](size_t bytes) -> void* {
        void* p = w + off;
        off = (off + bytes + 255) & ~(size_t)255;
        return p;
    };
    unsigned short* go_h = (unsigned short*)alloc((size_t)G * HID * 2);
    unsigned short* hcat = (unsigned short*)alloc((size_t)N * 512 * 2);
    unsigned short* tmp  = (unsigned short*)alloc((size_t)N * HID * 2);
    int* counts  = (int*)alloc((size_t)N * 4);
    int* offsets = (int*)alloc((size_t)N * 4);
    int* cursor  = (int*)alloc((size_t)N * 4);
    int* nbr     = (int*)alloc((size_t)E * 4);

    hipMemsetAsync(counts, 0, (size_t)N * 4, stream);

    go_proj_kernel<<<dim3((G + 15) / 16), dim3(256), 0, stream>>>(go_x, Wg, bg, go_h, G);
    hist_kernel<<<dim3(1024), dim3(256), 0, stream>>>(dst, counts, E);
    scan_kernel<<<dim3(1), dim3(1024), 0, stream>>>(counts, offsets, cursor, N);
    scatter_kernel<<<dim3(1024), dim3(256), 0, stream>>>(dst, src, cursor, nbr, E);
    cast_prot_kernel<<<dim3(2048), dim3(256), 0, stream>>>(prot, hcat, N);
    agg_kernel<<<dim3(N), dim3(64), 0, stream>>>(go_h, counts, offsets, nbr, hcat, N);
    mlp1_kernel<<<dim3((N + 15) / 16), dim3(256), 0, stream>>>(hcat, W1, b1, tmp, N);
    mlp2_ln_kernel<<<dim3((N + 15) / 16), dim3(256), 0, stream>>>(tmp, W2, b2, prot, counts, gamma, beta, (float*)d_out, N);
}

// Round 4
// 672.610 us; speedup vs baseline: 1.4210x; 1.4210x over previous
//
#include <hip/hip_runtime.h>
#include <hip/hip_bf16.h>
#include <stdint.h>

#define HID 256
#define GOD 200
#define LN_EPS 1e-5f

typedef __attribute__((ext_vector_type(8))) short short8;
typedef __attribute__((ext_vector_type(4))) float f32x4;

__device__ __forceinline__ float bf2f(unsigned short u) {
    union { unsigned int i; float f; } c; c.i = ((unsigned int)u) << 16; return c.f;
}
__device__ __forceinline__ unsigned short f2bf(float f) {
    union { float f; unsigned int i; } c; c.f = f;
    unsigned int x = c.i;
    return (unsigned short)((x + 0x7fffu + ((x >> 16) & 1u)) >> 16);
}
__device__ __forceinline__ unsigned int pack2(float a, float b) {
    return (unsigned int)f2bf(a) | ((unsigned int)f2bf(b) << 16);
}
__device__ __forceinline__ short8 pack8(float4 a, float4 b) {
    short8 r;
    r[0] = (short)f2bf(a.x); r[1] = (short)f2bf(a.y);
    r[2] = (short)f2bf(a.z); r[3] = (short)f2bf(a.w);
    r[4] = (short)f2bf(b.x); r[5] = (short)f2bf(b.y);
    r[6] = (short)f2bf(b.z); r[7] = (short)f2bf(b.w);
    return r;
}

// ---------------- weight transpose + bf16 cast: Wt[c][k] = bf16(W[k][c]) ----------------
__global__ void transpose_w_kernel(const float* __restrict__ W, short* __restrict__ Wt,
                                   int K, int C, int Kp) {
    int total = C * Kp;
    for (int idx = blockIdx.x * 256 + threadIdx.x; idx < total; idx += gridDim.x * 256) {
        int c = idx / Kp, k = idx - c * Kp;
        float v = (k < K) ? W[(size_t)k * C + c] : 0.f;
        Wt[idx] = (short)f2bf(v);
    }
}

// ---------------- MFMA GEMM: out[M x 256] = epi(A[M x K'] @ Bt^T + bias) ----------------
// Bt is [256][K] bf16 (row-major, i.e. B transposed). Tile 128x128, 4 waves, 4x4 frags/wave.
// EPI 0: relu -> bf16 out.  EPI 1: prot + present*(acc+bias) -> f32 out.
template<int K, int ASTRIDE, int AK, bool AF32, int EPI>
__global__ __launch_bounds__(256) void gemm_mfma(
        const void* __restrict__ Ap, const short* __restrict__ Bt,
        const float* __restrict__ bias, void* __restrict__ outp,
        const float* __restrict__ prot, const int* __restrict__ counts, int M) {
    __shared__ short As[128][88];   // stride 88 shorts = 176 B: 16B-aligned, 2-way banks
    __shared__ short Bs[128][88];

    const int t = threadIdx.x;
    const int row0 = blockIdx.x * 128;
    const int col0 = blockIdx.y * 128;
    const int lane = t & 63, w = t >> 6, wr = w >> 1, wc = w & 1;

    f32x4 acc[4][4] = {};

    for (int kt = 0; kt < K / 64; ++kt) {
        const int k0 = kt * 64;
        short8 ar[4], br[4];
#pragma unroll
        for (int i = 0; i < 4; ++i) {
            int seg = t + i * 256;
            int r = seg >> 3, co = (seg & 7) * 8;
            if (AF32) {
                short8 v = {};
                if (row0 + r < M && k0 + co + 8 <= AK) {
                    const float* ap = (const float*)Ap + (size_t)(row0 + r) * ASTRIDE + k0 + co;
                    float4 f0 = *(const float4*)ap;
                    float4 f1 = *(const float4*)(ap + 4);
                    v = pack8(f0, f1);
                }
                ar[i] = v;
            } else {
                short8 v = {};
                if (row0 + r < M)
                    v = *(const short8*)((const short*)Ap + (size_t)(row0 + r) * ASTRIDE + k0 + co);
                ar[i] = v;
            }
            br[i] = *(const short8*)(Bt + (size_t)(col0 + r) * K + k0 + co);
        }
        __syncthreads();
#pragma unroll
        for (int i = 0; i < 4; ++i) {
            int seg = t + i * 256;
            int r = seg >> 3, co = (seg & 7) * 8;
            *(short8*)&As[r][co] = ar[i];
            *(short8*)&Bs[r][co] = br[i];
        }
        __syncthreads();
#pragma unroll
        for (int ks = 0; ks < 2; ++ks) {
            short8 af[4], bf[4];
#pragma unroll
            for (int mt = 0; mt < 4; ++mt)
                af[mt] = *(const short8*)&As[wr * 64 + mt * 16 + (lane & 15)][ks * 32 + (lane >> 4) * 8];
#pragma unroll
            for (int nt = 0; nt < 4; ++nt)
                bf[nt] = *(const short8*)&Bs[wc * 64 + nt * 16 + (lane & 15)][ks * 32 + (lane >> 4) * 8];
#pragma unroll
            for (int mt = 0; mt < 4; ++mt)
#pragma unroll
                for (int nt = 0; nt < 4; ++nt)
                    acc[mt][nt] = __builtin_amdgcn_mfma_f32_16x16x32_bf16(af[mt], bf[nt], acc[mt][nt], 0, 0, 0);
        }
    }

    // epilogue: D col = lane&15, row = (lane>>4)*4 + reg  [m89-verified]
#pragma unroll
    for (int nt = 0; nt < 4; ++nt) {
        int cg = col0 + wc * 64 + nt * 16 + (lane & 15);
        float bb = bias[cg];
#pragma unroll
        for (int mt = 0; mt < 4; ++mt) {
            int rbase = row0 + wr * 64 + mt * 16 + ((lane >> 4) * 4);
#pragma unroll
            for (int j = 0; j < 4; ++j) {
                int rg = rbase + j;
                if (rg < M) {
                    float v = acc[mt][nt][j] + bb;
                    if (EPI == 0) {
                        ((unsigned short*)outp)[(size_t)rg * 256 + cg] = f2bf(fmaxf(v, 0.f));
                    } else {
                        float pres = (counts[rg] > 0) ? 1.f : 0.f;
                        ((float*)outp)[(size_t)rg * 256 + cg] =
                            prot[(size_t)rg * 256 + cg] + pres * v;
                    }
                }
            }
        }
    }
}

// ---------------- CSR build ----------------
__global__ void hist_kernel(const int* __restrict__ dst, int* __restrict__ counts, int E) {
    for (int e = blockIdx.x * blockDim.x + threadIdx.x; e < E; e += gridDim.x * blockDim.x)
        atomicAdd(&counts[dst[e]], 1);
}

__global__ __launch_bounds__(1024) void scan_kernel(
        const int* __restrict__ counts, int* __restrict__ offsets,
        int* __restrict__ cursor, int N) {
    __shared__ int wsum[16];
    __shared__ int carry_s;
    int tid = threadIdx.x, lane = tid & 63, wid = tid >> 6;
    if (tid == 0) carry_s = 0;
    __syncthreads();
    for (int base = 0; base < N; base += 1024) {
        int i = base + tid;
        int v = (i < N) ? counts[i] : 0;
        int s = v;
#pragma unroll
        for (int o = 1; o < 64; o <<= 1) { int y = __shfl_up(s, o); if (lane >= o) s += y; }
        if (lane == 63) wsum[wid] = s;
        __syncthreads();
        if (wid == 0) {
            int wv = (lane < 16) ? wsum[lane] : 0;
            int t2 = wv;
#pragma unroll
            for (int o = 1; o < 16; o <<= 1) { int y = __shfl_up(t2, o); if (lane >= o) t2 += y; }
            if (lane < 16) wsum[lane] = t2 - wv;  // exclusive wave prefix
        }
        __syncthreads();
        int excl = carry_s + wsum[wid] + (s - v);
        if (i < N) { offsets[i] = excl; cursor[i] = excl; }
        __syncthreads();
        if (tid == 1023) carry_s += wsum[15] + s;
        __syncthreads();
    }
}

__global__ void scatter_kernel(const int* __restrict__ dst, const int* __restrict__ src,
                               int* __restrict__ cursor, int* __restrict__ nbr, int E) {
    for (int e = blockIdx.x * blockDim.x + threadIdx.x; e < E; e += gridDim.x * blockDim.x) {
        int d = dst[e];
        int slot = atomicAdd(&cursor[d], 1);
        nbr[slot] = src[e];
    }
}

// ---------------- prot_emb -> bf16 into hcat[:, :256] ----------------
__global__ void cast_prot_kernel(const float* __restrict__ prot,
                                 unsigned short* __restrict__ hcat, int N) {
    int total = N * 128;
    for (int i = blockIdx.x * blockDim.x + threadIdx.x; i < total; i += gridDim.x * blockDim.x) {
        int row = i >> 7, cp = i & 127;
        float2 f = ((const float2*)prot)[(size_t)row * 128 + cp];
        ((unsigned int*)hcat)[(size_t)row * 256 + cp] = pack2(f.x, f.y);
    }
}

// ---------------- scatter-mean: one wave per protein ----------------
__global__ void agg_kernel(const unsigned short* __restrict__ go_h,
                           const int* __restrict__ counts, const int* __restrict__ offsets,
                           const int* __restrict__ nbr, unsigned short* __restrict__ hcat, int N) {
    int p = blockIdx.x;
    if (p >= N) return;
    int lane = threadIdx.x;  // 64
    int deg = counts[p], off = offsets[p];
    float a0 = 0.f, a1 = 0.f, a2 = 0.f, a3 = 0.f;
    for (int i = 0; i < deg; ++i) {
        int g = nbr[off + i];
        ushort4 u = *(const ushort4*)(go_h + (size_t)g * HID + lane * 4);
        a0 += bf2f(u.x); a1 += bf2f(u.y); a2 += bf2f(u.z); a3 += bf2f(u.w);
    }
    float inv = 1.f / (float)max(deg, 1);
    unsigned short* d = hcat + (size_t)p * 512 + HID + lane * 4;
    *(unsigned int*)(d)     = pack2(a0 * inv, a1 * inv);
    *(unsigned int*)(d + 2) = pack2(a2 * inv, a3 * inv);
}

// ---------------- LayerNorm over y[N][256] f32 -> out ----------------
__global__ __launch_bounds__(256) void ln_kernel(
        const float* __restrict__ y, const float* __restrict__ gamma,
        const float* __restrict__ beta, float* __restrict__ out, int N) {
    int lane = threadIdx.x & 63;
    int row = blockIdx.x * 4 + (threadIdx.x >> 6);
    if (row >= N) return;
    float4 v = ((const float4*)(y + (size_t)row * 256))[lane];
    float s = v.x + v.y + v.z + v.w;
#pragma unroll
    for (int o = 32; o >= 1; o >>= 1) s += __shfl_xor(s, o);
    float mu = s * (1.f / 256.f);
    float4 d; d.x = v.x - mu; d.y = v.y - mu; d.z = v.z - mu; d.w = v.w - mu;
    float q = d.x * d.x + d.y * d.y + d.z * d.z + d.w * d.w;
#pragma unroll
    for (int o = 32; o >= 1; o >>= 1) q += __shfl_xor(q, o);
    float rstd = rsqrtf(q * (1.f / 256.f) + LN_EPS);
    float4 g = ((const float4*)gamma)[lane];
    float4 b = ((const float4*)beta)[lane];
    float4 o4;
    o4.x = d.x * rstd * g.x + b.x; o4.y = d.y * rstd * g.y + b.y;
    o4.z = d.z * rstd * g.z + b.z; o4.w = d.w * rstd * g.w + b.w;
    ((float4*)(out + (size_t)row * 256))[lane] = o4;
}

extern "C" void kernel_launch(void* const* d_in, const int* in_sizes, int n_in,
                              void* d_out, int out_size, void* d_ws, size_t ws_size,
                              hipStream_t stream) {
    const float* prot  = (const float*)d_in[0];
    const float* go_x  = (const float*)d_in[1];
    const int*   edges = (const int*)d_in[2];
    const float* Wg    = (const float*)d_in[4];
    const float* bg    = (const float*)d_in[5];
    const float* W1    = (const float*)d_in[6];
    const float* b1    = (const float*)d_in[7];
    const float* W2    = (const float*)d_in[8];
    const float* b2    = (const float*)d_in[9];
    const float* gamma = (const float*)d_in[10];
    const float* beta  = (const float*)d_in[11];

    int N = in_sizes[0] / HID;
    int G = in_sizes[1] / GOD;
    int E = in_sizes[2] / 2;
    const int* dst = edges;
    const int* src = edges + E;

    uint8_t* w = (uint8_t*)d_ws;
    size_t off = 0;
    auto alloc = [&](size_t bytes) -> void* {
        void* p = w + off;
        off = (off + bytes + 255) & ~(size_t)255;
        return p;
    };
    unsigned short* go_h = (unsigned short*)alloc((size_t)G * HID * 2);
    unsigned short* hcat = (unsigned short*)alloc((size_t)N * 512 * 2);
    unsigned short* tmp  = (unsigned short*)alloc((size_t)N * HID * 2);
    int* counts  = (int*)alloc((size_t)N * 4);
    int* offsets = (int*)alloc((size_t)N * 4);
    int* cursor  = (int*)alloc((size_t)N * 4);
    int* nbr     = (int*)alloc((size_t)E * 4);
    short* Wgt = (short*)alloc((size_t)256 * 256 * 2);
    short* W1t = (short*)alloc((size_t)256 * 512 * 2);
    short* W2t = (short*)alloc((size_t)256 * 256 * 2);
    float* y = (float*)hcat;  // reuse: hcat dead after mlp1, y written by mlp2

    hipMemsetAsync(counts, 0, (size_t)N * 4, stream);

    transpose_w_kernel<<<dim3(256), dim3(256), 0, stream>>>(Wg, Wgt, GOD, 256, 256);
    transpose_w_kernel<<<dim3(512), dim3(256), 0, stream>>>(W1, W1t, 512, 256, 512);
    transpose_w_kernel<<<dim3(256), dim3(256), 0, stream>>>(W2, W2t, 256, 256, 256);

    int rb = (N + 127) / 128;           // 391 (N == G here, both 50000)
    int rbg = (G + 127) / 128;

    // go_h = relu(go_x @ Wg + bg)   [A f32, K padded 200->256]
    gemm_mfma<256, GOD, GOD, true, 0><<<dim3(rbg, 2), dim3(256), 0, stream>>>(
        go_x, Wgt, bg, go_h, nullptr, nullptr, G);

    hist_kernel<<<dim3(1024), dim3(256), 0, stream>>>(dst, counts, E);
    scan_kernel<<<dim3(1), dim3(1024), 0, stream>>>(counts, offsets, cursor, N);
    scatter_kernel<<<dim3(1024), dim3(256), 0, stream>>>(dst, src, cursor, nbr, E);
    cast_prot_kernel<<<dim3(2048), dim3(256), 0, stream>>>(prot, hcat, N);
    agg_kernel<<<dim3(N), dim3(64), 0, stream>>>(go_h, counts, offsets, nbr, hcat, N);

    // tmp = relu(hcat @ W1 + b1)
    gemm_mfma<512, 512, 512, false, 0><<<dim3(rb, 2), dim3(256), 0, stream>>>(
        hcat, W1t, b1, tmp, nullptr, nullptr, N);

    // y = prot + present * (tmp @ W2 + b2)
    gemm_mfma<256, 256, 256, false, 1><<<dim3(rb, 2), dim3(256), 0, stream>>>(
        tmp, W2t, b2, y, prot, counts, N);

    ln_kernel<<<dim3((N + 3) / 4), dim3(256), 0, stream>>>(y, gamma, beta, (float*)d_out, N);
}